// Round 13
// baseline (178.100 us; speedup 1.0000x reference)
//
#include <hip/hip_runtime.h>
#include <math.h>

// N=4, C=256, H=W=32, NH=2, HD=128, MAX_DIS=7, WS=15, WW=225, T=sqrt(128)
// out: [hw=1024][n=4][c=256] fp32

typedef __attribute__((ext_vector_type(8))) short short8;
typedef __attribute__((ext_vector_type(4))) float floatx4;

__device__ __forceinline__ short f2bf(float f) {
    unsigned u = __float_as_uint(f);
    unsigned r = (u + 0x7fffu + ((u >> 16) & 1u)) >> 16;
    return (short)r;
}
__device__ __forceinline__ float bf2f(short s) {
    return __uint_as_float(((unsigned)(unsigned short)s) << 16);
}

// ---------------------------------------------------------------------------
// conv_kernel: build bf16 hi/lo MFMA fragment layouts.
// z 0..11 : inputs q/k/v  -> B-frags Xhi/Xlo
// z 12..15: weights Wq,Wk,Wv,Wfc -> A-frags Whi/Wlo
// z 16..17: Wrel per head -> A-frags Wrh/Wrl (15 w-tiles, zero-padded)
// ---------------------------------------------------------------------------
__global__ __launch_bounds__(256)
void conv_kernel(const float* __restrict__ q, const float* __restrict__ k,
                 const float* __restrict__ v,
                 const float* __restrict__ Wq, const float* __restrict__ Wk,
                 const float* __restrict__ Wv, const float* __restrict__ Wfc,
                 const float* __restrict__ Wrel,
                 short* __restrict__ Xhi, short* __restrict__ Xlo,
                 short* __restrict__ Whi, short* __restrict__ Wlo,
                 short* __restrict__ Wrh, short* __restrict__ Wrl)
{
    const int tid = threadIdx.x;
    const int z = blockIdx.z;
    const int lane = tid & 63;
    const int n16 = lane & 15, quad = lane >> 4;

    if (z < 12) {
        __shared__ float st[64 * 33];
        const int sel = z >> 2, batch = z & 3;
        const float* X = (sel == 0 ? q : sel == 1 ? k : v) + ((long)batch << 18);
        const int mb = blockIdx.x, kc = blockIdx.y;
#pragma unroll
        for (int it = 0; it < 8; ++it) {
            int e = tid + it * 256;
            int cc = e >> 6, mm = e & 63;
            st[mm * 33 + cc] = X[((long)(kc * 32 + cc) << 10) + mb * 64 + mm];
        }
        __syncthreads();
        const int mtl = tid >> 6;
        const int m = mtl * 16 + n16;
        short h[8], l[8];
#pragma unroll
        for (int j = 0; j < 8; ++j) {
            float f = st[m * 33 + quad * 8 + j];
            short hb = f2bf(f);
            h[j] = hb;
            l[j] = f2bf(f - bf2f(hb));
        }
        int mt16 = mb * 4 + mtl;
        long off = (long)z * 262144 + (((long)(mt16 * 8 + kc) * 64) + lane) * 8;
        *(short8*)(Xhi + off) = *(short8*)&h[0];
        *(short8*)(Xlo + off) = *(short8*)&l[0];
    } else if (z < 16) {
        if (tid >= 64) return;
        const int w = z - 12;
        const float* W = (w == 0 ? Wq : w == 1 ? Wk : w == 2 ? Wv : Wfc);
        const int dt = blockIdx.x, kc = blockIdx.y;
        const int d = dt * 16 + n16, cb = kc * 32 + quad * 8;
        float4 w0 = *(const float4*)&W[d * 256 + cb];
        float4 w1 = *(const float4*)&W[d * 256 + cb + 4];
        float f[8] = {w0.x, w0.y, w0.z, w0.w, w1.x, w1.y, w1.z, w1.w};
        short h[8], l[8];
#pragma unroll
        for (int j = 0; j < 8; ++j) {
            short hb = f2bf(f[j]);
            h[j] = hb;
            l[j] = f2bf(f[j] - bf2f(hb));
        }
        long off = (long)w * 65536 + (((long)(dt * 8 + kc) * 64) + lane) * 8;
        *(short8*)(Whi + off) = *(short8*)&h[0];
        *(short8*)(Wlo + off) = *(short8*)&l[0];
    } else {
        if (tid >= 64) return;
        const int g = z - 16;
        const int wt = blockIdx.x, kc = blockIdx.y;
        if (wt >= 15 || kc >= 4) return;
        const int w = wt * 16 + n16;         // 0..239, valid < 225
        const int cb = kc * 32 + quad * 8;
        float f[8] = {0.f, 0.f, 0.f, 0.f, 0.f, 0.f, 0.f, 0.f};
        if (w < 225) {
            float4 w0 = *(const float4*)&Wrel[(long)(g * 225 + w) * 128 + cb];
            float4 w1 = *(const float4*)&Wrel[(long)(g * 225 + w) * 128 + cb + 4];
            f[0] = w0.x; f[1] = w0.y; f[2] = w0.z; f[3] = w0.w;
            f[4] = w1.x; f[5] = w1.y; f[6] = w1.z; f[7] = w1.w;
        }
        short h[8], l[8];
#pragma unroll
        for (int j = 0; j < 8; ++j) {
            short hb = f2bf(f[j]);
            h[j] = hb;
            l[j] = f2bf(f[j] - bf2f(hb));
        }
        long off = (long)g * 30720 + (((long)(wt * 4 + kc) * 64) + lane) * 8;
        *(short8*)(Wrh + off) = *(short8*)&h[0];
        *(short8*)(Wrl + off) = *(short8*)&l[0];
    }
}

// ---------------------------------------------------------------------------
// mfma_proj: Y = W·X for q/k/v with hi/lo split (3 MFMAs per k-chunk).
// grid (mb 16, db 4, z 12). Epilogues:
//   sel 0/1: LDS transpose -> x-major bf16 hi/lo (q unscaled, k * 1/T)
//   sel 2  : fp32 -> padded vpad layout + zero this block's pad columns
// ---------------------------------------------------------------------------
__global__ __launch_bounds__(256)
void mfma_proj(const short* __restrict__ Xhi, const short* __restrict__ Xlo,
               const short* __restrict__ Whi, const short* __restrict__ Wlo,
               const float* __restrict__ bq, const float* __restrict__ bk,
               const float* __restrict__ bv,
               short* __restrict__ qhi, short* __restrict__ qlo,
               short* __restrict__ khi, short* __restrict__ klo,
               float* __restrict__ vpad)
{
    __shared__ float tile[64 * 65];
    const int tid = threadIdx.x;
    const int wave = tid >> 6, lane = tid & 63;
    const int n16 = lane & 15, quad = lane >> 4;
    const int mb = blockIdx.x, db = blockIdx.y, z = blockIdx.z;
    const int sel = z >> 2, batch = z & 3;
    const int dt = db * 4 + wave;

    const short* Ah = Whi + (long)sel * 65536 + ((long)(dt * 8) * 64 + lane) * 8;
    const short* Al = Wlo + (long)sel * 65536 + ((long)(dt * 8) * 64 + lane) * 8;
    short8 ahi[8], alo[8];
#pragma unroll
    for (int kc = 0; kc < 8; ++kc) {
        ahi[kc] = *(const short8*)(Ah + kc * 512);
        alo[kc] = *(const short8*)(Al + kc * 512);
    }
    const short* Bh = Xhi + (long)z * 262144;
    const short* Bl = Xlo + (long)z * 262144;

    const float* bias = (sel == 0 ? bq : sel == 1 ? bk : bv);
    float4 bv4 = *(const float4*)&bias[dt * 16 + quad * 4];
    float bb[4] = {bv4.x, bv4.y, bv4.z, bv4.w};

    if (sel == 2) {
#pragma unroll
        for (int mtl = 0; mtl < 4; ++mtl) {
            const int mt16 = mb * 4 + mtl;
            floatx4 acc = {0.f, 0.f, 0.f, 0.f};
#pragma unroll
            for (int kc = 0; kc < 8; ++kc) {
                long bo = ((long)(mt16 * 8 + kc) * 64 + lane) * 8;
                short8 bh = *(const short8*)(Bh + bo);
                short8 bl = *(const short8*)(Bl + bo);
                acc = __builtin_amdgcn_mfma_f32_16x16x32_bf16(ahi[kc], bh, acc, 0, 0, 0);
                acc = __builtin_amdgcn_mfma_f32_16x16x32_bf16(ahi[kc], bl, acc, 0, 0, 0);
                acc = __builtin_amdgcn_mfma_f32_16x16x32_bf16(alo[kc], bh, acc, 0, 0, 0);
            }
            const int m = mt16 * 16 + n16;
            float* Y = vpad + (long)batch * 393216;
            const int row = m >> 5, col = (m & 31) + 8;
#pragma unroll
            for (int r = 0; r < 4; ++r)
                Y[(long)(dt * 16 + quad * 4 + r) * 1536 + row * 48 + col] = acc[r] + bb[r];
        }
        // zero the pad columns for this block's (ch, row) range
        {
            float* Y = vpad + (long)batch * 393216;
            const int ch_l = tid >> 2, rest = tid & 3;
            const int prow = rest >> 1, side = rest & 1;
            long po = (long)(db * 64 + ch_l) * 1536 + (mb * 2 + prow) * 48 + side * 40;
            float4 z4 = make_float4(0.f, 0.f, 0.f, 0.f);
            *(float4*)&Y[po] = z4;
            *(float4*)&Y[po + 4] = z4;
        }
        return;
    }

#pragma unroll
    for (int mtl = 0; mtl < 4; ++mtl) {
        const int mt16 = mb * 4 + mtl;
        floatx4 acc = {0.f, 0.f, 0.f, 0.f};
#pragma unroll
        for (int kc = 0; kc < 8; ++kc) {
            long bo = ((long)(mt16 * 8 + kc) * 64 + lane) * 8;
            short8 bh = *(const short8*)(Bh + bo);
            short8 bl = *(const short8*)(Bl + bo);
            acc = __builtin_amdgcn_mfma_f32_16x16x32_bf16(ahi[kc], bh, acc, 0, 0, 0);
            acc = __builtin_amdgcn_mfma_f32_16x16x32_bf16(ahi[kc], bl, acc, 0, 0, 0);
            acc = __builtin_amdgcn_mfma_f32_16x16x32_bf16(alo[kc], bh, acc, 0, 0, 0);
        }
        const int ml = mtl * 16 + n16;
        const int cl = wave * 16 + quad * 4;
#pragma unroll
        for (int r = 0; r < 4; ++r)
            tile[ml * 65 + cl + r] = acc[r] + bb[r];
    }
    __syncthreads();

    const float scale = (sel == 1) ? 0.08838834764831845f : 1.0f;
    const int m_l = tid >> 2, c16 = (tid & 3) * 16;
    const int m = mb * 64 + m_l;
    const int cglob = db * 64 + c16;
    const int g = cglob >> 7, ch = cglob & 127;
    const long base = (((long)(batch * 2 + g) << 10) + m) * 128 + ch;
    short h[16], l[16];
#pragma unroll
    for (int j = 0; j < 16; ++j) {
        float f = tile[m_l * 65 + c16 + j] * scale;
        short hb = f2bf(f);
        h[j] = hb;
        l[j] = f2bf(f - bf2f(hb));
    }
    short* oh = sel ? khi : qhi;
    short* ol = sel ? klo : qlo;
    *(short8*)(oh + base)     = *(short8*)&h[0];
    *(short8*)(oh + base + 8) = *(short8*)&h[8];
    *(short8*)(ol + base)     = *(short8*)&l[0];
    *(short8*)(ol + base + 8) = *(short8*)&l[8];
}

// ---------------------------------------------------------------------------
// scores_pv: fully fused rel + band-QK^T + softmax + PV + V_bias + frag store.
// block = (y, x-tile 16px, bz), grid (64, 8). This block's 16 px are exactly
// the queries whose attention it needs for PV -> no global attn round-trip.
// LDS: qk[16*241] (15.4K) + pa[225*16] (14.4K) ~= 30 KB.
// ---------------------------------------------------------------------------
__global__ __launch_bounds__(256)
void scores_pv(const short* __restrict__ qhi, const short* __restrict__ qlo,
               const short* __restrict__ khi, const short* __restrict__ klo,
               const short* __restrict__ Wrh, const short* __restrict__ Wrl,
               const float* __restrict__ brel,
               const float* __restrict__ vpad, const float* __restrict__ Vbias,
               short* __restrict__ AGhi, short* __restrict__ AGlo)
{
    __shared__ float qk[16 * 241];
    __shared__ __align__(16) float pa[225 * 16];
    __shared__ float invl[16];

    const int tid = threadIdx.x;
    const int wave = tid >> 6, lane = tid & 63;
    const int y  = blockIdx.x >> 1;
    const int xt = blockIdx.x & 1;
    const int bz = blockIdx.y;
    const int n = bz >> 1, g = bz & 1;
    const int x0 = xt * 16;

    const int n16 = lane & 15, quad = lane >> 4;
    const long qbase = (((long)bz << 10) + y * 32 + x0 + n16) * 128 + quad * 8;
    short8 a_hi[4], a_lo[4];
#pragma unroll
    for (int ch = 0; ch < 4; ++ch) {
        a_hi[ch] = *(const short8*)(qhi + qbase + ch * 32);
        a_lo[ch] = *(const short8*)(qlo + qbase + ch * 32);
    }

    // ---- phase R: rel logits (A = Wrel frags, B = q frags) ----
    for (int wt = wave; wt < 15; wt += 4) {
        const short* Ah = Wrh + (long)g * 30720 + ((long)(wt * 4) * 64 + lane) * 8;
        const short* Al = Wrl + (long)g * 30720 + ((long)(wt * 4) * 64 + lane) * 8;
        floatx4 racc = {0.f, 0.f, 0.f, 0.f};
#pragma unroll
        for (int kc = 0; kc < 4; ++kc) {
            short8 whh = *(const short8*)(Ah + kc * 512);
            short8 wll = *(const short8*)(Al + kc * 512);
            racc = __builtin_amdgcn_mfma_f32_16x16x32_bf16(whh, a_hi[kc], racc, 0, 0, 0);
            racc = __builtin_amdgcn_mfma_f32_16x16x32_bf16(whh, a_lo[kc], racc, 0, 0, 0);
            racc = __builtin_amdgcn_mfma_f32_16x16x32_bf16(wll, a_hi[kc], racc, 0, 0, 0);
        }
#pragma unroll
        for (int r = 0; r < 4; ++r) {
            int w = wt * 16 + quad * 4 + r;
            if (w < 225) {
                int dy = w / 15, dx = w - dy * 15;
                qk[n16 * 241 + dy * 16 + dx] = racc[r] + brel[g * 225 + w];
            }
        }
    }
    __syncthreads();

    // ---- phase M: mask invalid neighbors and pad slots ----
    for (int e = tid; e < 16 * 241; e += 256) {
        int px = e / 241, idx = e - px * 241;
        int dy = idx >> 4, dx = idx & 15;
        int hy = y + dy - 7, hx = x0 + px + dx - 7;
        bool valid = (dx < 15) && (dy < 15) &&
                     (hy >= 0) && (hy < 32) && (hx >= 0) && (hx < 32);
        if (!valid) qk[e] = -1e8f;
    }
    __syncthreads();

    // ---- phase B: band QK^T, accumulate into qk ----
    for (int dy = wave; dy < 15; dy += 4) {
        const int ky = y + dy - 7;
        if (ky < 0 || ky > 31) continue;
#pragma unroll
        for (int kxt = 0; kxt < 2; ++kxt) {
            const int kxg = x0 - 8 + kxt * 16 + n16;
            const long kb = (((long)bz << 10) + ky * 32 + kxg) * 128 + quad * 8;
            floatx4 acc = {0.f, 0.f, 0.f, 0.f};
#pragma unroll
            for (int ch = 0; ch < 4; ++ch) {
                short8 b_hi = *(const short8*)(khi + kb + ch * 32);
                short8 b_lo = *(const short8*)(klo + kb + ch * 32);
                acc = __builtin_amdgcn_mfma_f32_16x16x32_bf16(a_hi[ch], b_hi, acc, 0, 0, 0);
                acc = __builtin_amdgcn_mfma_f32_16x16x32_bf16(a_hi[ch], b_lo, acc, 0, 0, 0);
                acc = __builtin_amdgcn_mfma_f32_16x16x32_bf16(a_lo[ch], b_hi, acc, 0, 0, 0);
            }
            if (kxg >= 0 && kxg < 32) {
#pragma unroll
                for (int r = 0; r < 4; ++r) {
                    int m = quad * 4 + r;
                    int dx = kxg - (x0 + m) + 7;
                    if (dx >= 0 && dx < 15) {
                        int s = m * 241 + dy * 16 + dx;
                        qk[s] = qk[s] + acc[r];
                    }
                }
            }
        }
    }
    __syncthreads();

    // ---- softmax over 240 slots: 16 threads per px ----
    {
        int px = tid >> 4, s = tid & 15;
        float mx = -3.0e38f;
        for (int w = s; w < 240; w += 16) mx = fmaxf(mx, qk[px * 241 + w]);
#pragma unroll
        for (int msk = 8; msk; msk >>= 1) mx = fmaxf(mx, __shfl_xor(mx, msk));
        float sum = 0.f;
        for (int w = s; w < 240; w += 16) {
            float p = __expf(qk[px * 241 + w] - mx);
            qk[px * 241 + w] = p;
            sum += p;
        }
#pragma unroll
        for (int msk = 8; msk; msk >>= 1) sum += __shfl_xor(sum, msk);
        if (s == 0) invl[px] = 1.0f / sum;
    }
    __syncthreads();

    // ---- transpose + normalize: pa[w][px] = attn ----
    for (int e = tid; e < 3600; e += 256) {
        int px = e & 15, w = e >> 4;
        int dy2 = w / 15, dx2 = w - dy2 * 15;
        pa[w * 16 + px] = qk[px * 241 + dy2 * 16 + dx2] * invl[px];
    }
    __syncthreads();        // qk now dead; pa live

    // ---- PV + V_bias: thread = (chg 64 -> 2 ch, xq 4 -> 4 px) ----
    const int chg = tid >> 2;            // 0..63
    const int xq  = tid & 3;
    const int c0  = chg * 2;             // channel within head (0..126)
    const int x0l = xq * 4;
    const int x0g = x0 + x0l;
    const float* v0 = vpad + (long)bz * 196608 + (long)c0 * 1536;
    const float* v1 = v0 + 1536;
    const float* b0 = Vbias + (g * 128 + c0) * 225;
    const float* b1 = b0 + 225;

    float acc0[4] = {0.f, 0.f, 0.f, 0.f};
    float acc1[4] = {0.f, 0.f, 0.f, 0.f};

    for (int dy = 0; dy < 15; ++dy) {
        int hy = y + dy - 7;
        if (hy < 0 || hy > 31) continue;           // p == 0 for this dy
        const float4* r0 = (const float4*)(v0 + hy * 48 + x0g);
        const float4* r1 = (const float4*)(v1 + hy * 48 + x0g);
        float wa[20], wb[20];
#pragma unroll
        for (int t = 0; t < 5; ++t) {
            float4 a = r0[t], b = r1[t];
            wa[4*t+0] = a.x; wa[4*t+1] = a.y; wa[4*t+2] = a.z; wa[4*t+3] = a.w;
            wb[4*t+0] = b.x; wb[4*t+1] = b.y; wb[4*t+2] = b.z; wb[4*t+3] = b.w;
        }
        const float* par = &pa[dy * 15 * 16 + x0l];
        const float* vb0 = b0 + dy * 15;
        const float* vb1 = b1 + dy * 15;
#pragma unroll
        for (int dx = 0; dx < 15; ++dx) {
            float4 p4 = *(const float4*)&par[dx * 16];
            float ba = vb0[dx], bb = vb1[dx];
            acc0[0] += p4.x * (wa[1 + dx] + ba);
            acc0[1] += p4.y * (wa[2 + dx] + ba);
            acc0[2] += p4.z * (wa[3 + dx] + ba);
            acc0[3] += p4.w * (wa[4 + dx] + ba);
            acc1[0] += p4.x * (wb[1 + dx] + bb);
            acc1[1] += p4.y * (wb[2 + dx] + bb);
            acc1[2] += p4.z * (wb[3 + dx] + bb);
            acc1[3] += p4.w * (wb[4 + dx] + bb);
        }
    }
    __syncthreads();        // pa reads done; reuse qk region as out tile

    float* tile = qk;       // [16 m][129 c]
#pragma unroll
    for (int i = 0; i < 4; ++i) {
        tile[(x0l + i) * 129 + c0 + 0] = acc0[i];
        tile[(x0l + i) * 129 + c0 + 1] = acc1[i];
    }
    __syncthreads();

    // ---- AG fragment store: mt16 = y*2+xt, kc = g*4 + kcp ----
    const int kcp = tid >> 6;           // 0..3
    const int c_loc = kcp * 32 + quad * 8;
    short h[8], l[8];
#pragma unroll
    for (int j = 0; j < 8; ++j) {
        float f = tile[n16 * 129 + c_loc + j];
        short hb = f2bf(f);
        h[j] = hb;
        l[j] = f2bf(f - bf2f(hb));
    }
    const int mt16 = y * 2 + xt;
    const int kc = g * 4 + kcp;
    long off = (long)n * 262144 + (((long)(mt16 * 8 + kc) * 64) + lane) * 8;
    *(short8*)(AGhi + off) = *(short8*)&h[0];
    *(short8*)(AGlo + off) = *(short8*)&l[0];
}

// ---------------------------------------------------------------------------
// mfma_fc: out[m][n][d] = Wfc·agg + bfc, interleaved store via LDS transpose.
// ---------------------------------------------------------------------------
__global__ __launch_bounds__(256)
void mfma_fc(const short* __restrict__ Ahi, const short* __restrict__ Alo,
             const short* __restrict__ Whi, const short* __restrict__ Wlo,
             const float* __restrict__ bfc, float* __restrict__ out)
{
    __shared__ float tile[64 * 68];
    const int tid = threadIdx.x;
    const int wave = tid >> 6, lane = tid & 63;
    const int n16 = lane & 15, quad = lane >> 4;
    const int mb = blockIdx.x, db = blockIdx.y, nz = blockIdx.z;
    const int dt = db * 4 + wave;

    const short* Ah = Whi + (long)3 * 65536 + ((long)(dt * 8) * 64 + lane) * 8;
    const short* Al = Wlo + (long)3 * 65536 + ((long)(dt * 8) * 64 + lane) * 8;
    short8 ahi[8], alo[8];
#pragma unroll
    for (int kc = 0; kc < 8; ++kc) {
        ahi[kc] = *(const short8*)(Ah + kc * 512);
        alo[kc] = *(const short8*)(Al + kc * 512);
    }
    const short* Bh = Ahi + (long)nz * 262144;
    const short* Bl = Alo + (long)nz * 262144;

    float4 bv4 = *(const float4*)&bfc[dt * 16 + quad * 4];
    float bb[4] = {bv4.x, bv4.y, bv4.z, bv4.w};

#pragma unroll
    for (int mtl = 0; mtl < 4; ++mtl) {
        const int mt16 = mb * 4 + mtl;
        floatx4 acc = {0.f, 0.f, 0.f, 0.f};
#pragma unroll
        for (int kc = 0; kc < 8; ++kc) {
            long bo = ((long)(mt16 * 8 + kc) * 64 + lane) * 8;
            short8 bh = *(const short8*)(Bh + bo);
            short8 bl = *(const short8*)(Bl + bo);
            acc = __builtin_amdgcn_mfma_f32_16x16x32_bf16(ahi[kc], bh, acc, 0, 0, 0);
            acc = __builtin_amdgcn_mfma_f32_16x16x32_bf16(ahi[kc], bl, acc, 0, 0, 0);
            acc = __builtin_amdgcn_mfma_f32_16x16x32_bf16(alo[kc], bh, acc, 0, 0, 0);
        }
        const int ml = mtl * 16 + n16;
        const int dl = wave * 16 + quad * 4;
#pragma unroll
        for (int r = 0; r < 4; ++r)
            tile[ml * 68 + dl + r] = acc[r] + bb[r];
    }
    __syncthreads();
#pragma unroll
    for (int it = 0; it < 16; ++it) {
        int e = tid + it * 256;
        int dd = e & 63, mm = e >> 6;
        out[(long)(mb * 64 + mm) * 1024 + nz * 256 + db * 64 + dd] = tile[mm * 68 + dd];
    }
}

// ---------------------------------------------------------------------------
// ws floats: vpad@2097152(1572864)
//   qhi@6561792 qlo@7086080 khi@7610368 klo@8134656 (as shorts, 524288 fl ea)
//   Xhi@8658944(1572864) Xlo@10231808 Whi@11804672(131072) Wlo@11935744
//   AGhi@12066816(524288) AGlo@12591104 Wrh@13115392(30720) Wrl@13146112
// ---------------------------------------------------------------------------
extern "C" void kernel_launch(void* const* d_in, const int* in_sizes, int n_in,
                              void* d_out, int out_size, void* d_ws, size_t ws_size,
                              hipStream_t stream)
{
    const float* q    = (const float*)d_in[0];
    const float* k    = (const float*)d_in[1];
    const float* v    = (const float*)d_in[2];
    const float* Wq   = (const float*)d_in[3];
    const float* bq   = (const float*)d_in[4];
    const float* Wk   = (const float*)d_in[5];
    const float* bk   = (const float*)d_in[6];
    const float* Wv   = (const float*)d_in[7];
    const float* bv   = (const float*)d_in[8];
    const float* Wrel = (const float*)d_in[9];
    const float* brel = (const float*)d_in[10];
    const float* Vb   = (const float*)d_in[11];
    const float* Wfc  = (const float*)d_in[12];
    const float* bfc  = (const float*)d_in[13];
    float* out = (float*)d_out;

    float* ws   = (float*)d_ws;
    float* vpad = ws + 2097152;
    short* qhi  = (short*)(ws + 6561792);
    short* qlo  = (short*)(ws + 7086080);
    short* khi  = (short*)(ws + 7610368);
    short* klo  = (short*)(ws + 8134656);
    short* Xhi  = (short*)(ws + 8658944);
    short* Xlo  = (short*)(ws + 10231808);
    short* Whi  = (short*)(ws + 11804672);
    short* Wlo  = (short*)(ws + 11935744);
    short* AGhi = (short*)(ws + 12066816);
    short* AGlo = (short*)(ws + 12591104);
    short* Wrh  = (short*)(ws + 13115392);
    short* Wrl  = (short*)(ws + 13146112);

    dim3 blk(256);

    // fragment conversion: inputs (z 0..11), weights (z 12..15), Wrel (16..17)
    conv_kernel<<<dim3(16, 8, 18), blk, 0, stream>>>(q, k, v, Wq, Wk, Wv, Wfc,
                                                     Wrel, Xhi, Xlo, Whi, Wlo,
                                                     Wrh, Wrl);

    // QKV projections via MFMA (vpad pads zeroed in-kernel): 768 blocks
    mfma_proj<<<dim3(16, 4, 12), blk, 0, stream>>>(Xhi, Xlo, Whi, Wlo,
                                                   bq, bk, bv,
                                                   qhi, qlo, khi, klo, vpad);

    // fused rel + scores + softmax + PV + frag store: 512 blocks
    scores_pv<<<dim3(64, 8), blk, 0, stream>>>(qhi, qlo, khi, klo,
                                               Wrh, Wrl, brel, vpad, Vb,
                                               AGhi, AGlo);

    // FC via MFMA, interleaved [m][n][c] store: 256 blocks
    mfma_fc<<<dim3(16, 4, 4), blk, 0, stream>>>(AGhi, AGlo, Whi, Wlo, bfc, out);
}

// Round 14
// 167.744 us; speedup vs baseline: 1.0617x; 1.0617x over previous
//
#include <hip/hip_runtime.h>
#include <math.h>

// N=4, C=256, H=W=32, NH=2, HD=128, MAX_DIS=7, WS=15, WW=225, T=sqrt(128)
// out: [hw=1024][n=4][c=256] fp32

typedef __attribute__((ext_vector_type(8))) short short8;
typedef __attribute__((ext_vector_type(4))) short short4v;
typedef __attribute__((ext_vector_type(4))) float floatx4;

__device__ __forceinline__ short f2bf(float f) {
    unsigned u = __float_as_uint(f);
    unsigned r = (u + 0x7fffu + ((u >> 16) & 1u)) >> 16;
    return (short)r;
}
__device__ __forceinline__ float bf2f(short s) {
    return __uint_as_float(((unsigned)(unsigned short)s) << 16);
}

// ---------------------------------------------------------------------------
// conv_kernel: build bf16 hi/lo MFMA fragment layouts.
// z 0..11 : inputs q/k/v  -> B-frags Xhi/Xlo
// z 12..15: weights Wq,Wk,Wv,Wfc -> A-frags Whi/Wlo
// z 16..17: Wrel per head -> A-frags Wrh/Wrl (15 w-tiles, zero-padded)
// ---------------------------------------------------------------------------
__global__ __launch_bounds__(256)
void conv_kernel(const float* __restrict__ q, const float* __restrict__ k,
                 const float* __restrict__ v,
                 const float* __restrict__ Wq, const float* __restrict__ Wk,
                 const float* __restrict__ Wv, const float* __restrict__ Wfc,
                 const float* __restrict__ Wrel,
                 short* __restrict__ Xhi, short* __restrict__ Xlo,
                 short* __restrict__ Whi, short* __restrict__ Wlo,
                 short* __restrict__ Wrh, short* __restrict__ Wrl)
{
    const int tid = threadIdx.x;
    const int z = blockIdx.z;
    const int lane = tid & 63;
    const int n16 = lane & 15, quad = lane >> 4;

    if (z < 12) {
        __shared__ float st[64 * 33];
        const int sel = z >> 2, batch = z & 3;
        const float* X = (sel == 0 ? q : sel == 1 ? k : v) + ((long)batch << 18);
        const int mb = blockIdx.x, kc = blockIdx.y;
#pragma unroll
        for (int it = 0; it < 8; ++it) {
            int e = tid + it * 256;
            int cc = e >> 6, mm = e & 63;
            st[mm * 33 + cc] = X[((long)(kc * 32 + cc) << 10) + mb * 64 + mm];
        }
        __syncthreads();
        const int mtl = tid >> 6;
        const int m = mtl * 16 + n16;
        short h[8], l[8];
#pragma unroll
        for (int j = 0; j < 8; ++j) {
            float f = st[m * 33 + quad * 8 + j];
            short hb = f2bf(f);
            h[j] = hb;
            l[j] = f2bf(f - bf2f(hb));
        }
        int mt16 = mb * 4 + mtl;
        long off = (long)z * 262144 + (((long)(mt16 * 8 + kc) * 64) + lane) * 8;
        *(short8*)(Xhi + off) = *(short8*)&h[0];
        *(short8*)(Xlo + off) = *(short8*)&l[0];
    } else if (z < 16) {
        if (tid >= 64) return;
        const int w = z - 12;
        const float* W = (w == 0 ? Wq : w == 1 ? Wk : w == 2 ? Wv : Wfc);
        const int dt = blockIdx.x, kc = blockIdx.y;
        const int d = dt * 16 + n16, cb = kc * 32 + quad * 8;
        float4 w0 = *(const float4*)&W[d * 256 + cb];
        float4 w1 = *(const float4*)&W[d * 256 + cb + 4];
        float f[8] = {w0.x, w0.y, w0.z, w0.w, w1.x, w1.y, w1.z, w1.w};
        short h[8], l[8];
#pragma unroll
        for (int j = 0; j < 8; ++j) {
            short hb = f2bf(f[j]);
            h[j] = hb;
            l[j] = f2bf(f[j] - bf2f(hb));
        }
        long off = (long)w * 65536 + (((long)(dt * 8 + kc) * 64) + lane) * 8;
        *(short8*)(Whi + off) = *(short8*)&h[0];
        *(short8*)(Wlo + off) = *(short8*)&l[0];
    } else {
        if (tid >= 64) return;
        const int g = z - 16;
        const int wt = blockIdx.x, kc = blockIdx.y;
        if (wt >= 15 || kc >= 4) return;
        const int w = wt * 16 + n16;         // 0..239, valid < 225
        const int cb = kc * 32 + quad * 8;
        float f[8] = {0.f, 0.f, 0.f, 0.f, 0.f, 0.f, 0.f, 0.f};
        if (w < 225) {
            float4 w0 = *(const float4*)&Wrel[(long)(g * 225 + w) * 128 + cb];
            float4 w1 = *(const float4*)&Wrel[(long)(g * 225 + w) * 128 + cb + 4];
            f[0] = w0.x; f[1] = w0.y; f[2] = w0.z; f[3] = w0.w;
            f[4] = w1.x; f[5] = w1.y; f[6] = w1.z; f[7] = w1.w;
        }
        short h[8], l[8];
#pragma unroll
        for (int j = 0; j < 8; ++j) {
            short hb = f2bf(f[j]);
            h[j] = hb;
            l[j] = f2bf(f[j] - bf2f(hb));
        }
        long off = (long)g * 30720 + (((long)(wt * 4 + kc) * 64) + lane) * 8;
        *(short8*)(Wrh + off) = *(short8*)&h[0];
        *(short8*)(Wrl + off) = *(short8*)&l[0];
    }
}

// ---------------------------------------------------------------------------
// mfma_proj v2: one m-tile per block. grid (mt16 64, db 4, z 12) = 3072 blk.
// Epilogues: sel 0/1 -> x-major bf16 hi/lo (q unscaled, k * 1/T);
//            sel 2   -> padded vpad + zero this block's (row, side) pad.
// ---------------------------------------------------------------------------
__global__ __launch_bounds__(256)
void mfma_proj(const short* __restrict__ Xhi, const short* __restrict__ Xlo,
               const short* __restrict__ Whi, const short* __restrict__ Wlo,
               const float* __restrict__ bq, const float* __restrict__ bk,
               const float* __restrict__ bv,
               short* __restrict__ qhi, short* __restrict__ qlo,
               short* __restrict__ khi, short* __restrict__ klo,
               float* __restrict__ vpad)
{
    __shared__ float tile[16 * 65];
    const int tid = threadIdx.x;
    const int wave = tid >> 6, lane = tid & 63;
    const int n16 = lane & 15, quad = lane >> 4;
    const int mt16 = blockIdx.x, db = blockIdx.y, z = blockIdx.z;
    const int sel = z >> 2, batch = z & 3;
    const int dt = db * 4 + wave;

    const short* Ah = Whi + (long)sel * 65536 + ((long)(dt * 8) * 64 + lane) * 8;
    const short* Al = Wlo + (long)sel * 65536 + ((long)(dt * 8) * 64 + lane) * 8;
    const short* Bh = Xhi + (long)z * 262144;
    const short* Bl = Xlo + (long)z * 262144;

    const float* bias = (sel == 0 ? bq : sel == 1 ? bk : bv);
    float4 bv4 = *(const float4*)&bias[dt * 16 + quad * 4];
    float bb[4] = {bv4.x, bv4.y, bv4.z, bv4.w};

    floatx4 acc = {0.f, 0.f, 0.f, 0.f};
#pragma unroll
    for (int kc = 0; kc < 8; ++kc) {
        short8 ahi = *(const short8*)(Ah + kc * 512);
        short8 alo = *(const short8*)(Al + kc * 512);
        long bo = ((long)(mt16 * 8 + kc) * 64 + lane) * 8;
        short8 bh = *(const short8*)(Bh + bo);
        short8 bl = *(const short8*)(Bl + bo);
        acc = __builtin_amdgcn_mfma_f32_16x16x32_bf16(ahi, bh, acc, 0, 0, 0);
        acc = __builtin_amdgcn_mfma_f32_16x16x32_bf16(ahi, bl, acc, 0, 0, 0);
        acc = __builtin_amdgcn_mfma_f32_16x16x32_bf16(alo, bh, acc, 0, 0, 0);
    }

    if (sel == 2) {
        const int m = mt16 * 16 + n16;
        float* Y = vpad + (long)batch * 393216;
        const int row = m >> 5, col = (m & 31) + 8;
#pragma unroll
        for (int r = 0; r < 4; ++r)
            Y[(long)(dt * 16 + quad * 4 + r) * 1536 + row * 48 + col] = acc[r] + bb[r];
        // zero pad columns: this block handles (row = mt16>>1, side = mt16&1)
        {
            const int prow = mt16 >> 1, side = mt16 & 1;
            const int ch_l = tid >> 2, f2 = (tid & 3) * 2;
            long po = (long)(db * 64 + ch_l) * 1536 + prow * 48 + side * 40 + f2;
            Y[po] = 0.f;
            Y[po + 1] = 0.f;
        }
        return;
    }

    // sel 0/1: stage D[16 m][64 c] then x-major bf16 hi/lo
    const int cl = wave * 16 + quad * 4;
#pragma unroll
    for (int r = 0; r < 4; ++r)
        tile[n16 * 65 + cl + r] = acc[r] + bb[r];
    __syncthreads();

    const float scale = (sel == 1) ? 0.08838834764831845f : 1.0f;
    const int m_l = tid >> 4, c16 = (tid & 15) * 4;
    const int m = mt16 * 16 + m_l;
    const int cglob = db * 64 + c16;
    const int g = cglob >> 7, ch = cglob & 127;
    const long base = (((long)(batch * 2 + g) << 10) + m) * 128 + ch;
    short h[4], l[4];
#pragma unroll
    for (int j = 0; j < 4; ++j) {
        float f = tile[m_l * 65 + c16 + j] * scale;
        short hb = f2bf(f);
        h[j] = hb;
        l[j] = f2bf(f - bf2f(hb));
    }
    short* oh = sel ? khi : qhi;
    short* ol = sel ? klo : qlo;
    *(short4v*)(oh + base) = *(short4v*)&h[0];
    *(short4v*)(ol + base) = *(short4v*)&l[0];
}

// ---------------------------------------------------------------------------
// scores_mfma (round-12): rel fused. block = (y, x-tile 16px, bz), grid (64,8).
// Phase R: rel = Wrel·q (q frag doubles as B operand) -> qk LDS
// Phase M: mask; Phase B: band QK^T +=; softmax; attn writeback.
// ---------------------------------------------------------------------------
__global__ __launch_bounds__(256)
void scores_mfma(const short* __restrict__ qhi, const short* __restrict__ qlo,
                 const short* __restrict__ khi, const short* __restrict__ klo,
                 const short* __restrict__ Wrh, const short* __restrict__ Wrl,
                 const float* __restrict__ brel, float* __restrict__ attn)
{
    __shared__ float qk[16 * 241];
    __shared__ float invl[16];

    const int tid = threadIdx.x;
    const int wave = tid >> 6, lane = tid & 63;
    const int y  = blockIdx.x >> 1;
    const int xt = blockIdx.x & 1;
    const int bz = blockIdx.y;
    const int g = bz & 1;
    const int x0 = xt * 16;
    float* relh = attn + (long)bz * 230400;

    const int n16 = lane & 15, quad = lane >> 4;
    const long qbase = (((long)bz << 10) + y * 32 + x0 + n16) * 128 + quad * 8;
    short8 a_hi[4], a_lo[4];
#pragma unroll
    for (int ch = 0; ch < 4; ++ch) {
        a_hi[ch] = *(const short8*)(qhi + qbase + ch * 32);
        a_lo[ch] = *(const short8*)(qlo + qbase + ch * 32);
    }

    // ---- phase R: rel logits ----
    for (int wt = wave; wt < 15; wt += 4) {
        const short* Ah = Wrh + (long)g * 30720 + ((long)(wt * 4) * 64 + lane) * 8;
        const short* Al = Wrl + (long)g * 30720 + ((long)(wt * 4) * 64 + lane) * 8;
        floatx4 racc = {0.f, 0.f, 0.f, 0.f};
#pragma unroll
        for (int kc = 0; kc < 4; ++kc) {
            short8 whh = *(const short8*)(Ah + kc * 512);
            short8 wll = *(const short8*)(Al + kc * 512);
            racc = __builtin_amdgcn_mfma_f32_16x16x32_bf16(whh, a_hi[kc], racc, 0, 0, 0);
            racc = __builtin_amdgcn_mfma_f32_16x16x32_bf16(whh, a_lo[kc], racc, 0, 0, 0);
            racc = __builtin_amdgcn_mfma_f32_16x16x32_bf16(wll, a_hi[kc], racc, 0, 0, 0);
        }
#pragma unroll
        for (int r = 0; r < 4; ++r) {
            int w = wt * 16 + quad * 4 + r;
            if (w < 225) {
                int dy = w / 15, dx = w - dy * 15;
                qk[n16 * 241 + dy * 16 + dx] = racc[r] + brel[g * 225 + w];
            }
        }
    }
    __syncthreads();

    // ---- phase M: mask invalid neighbors and pad slots ----
    for (int e = tid; e < 16 * 241; e += 256) {
        int px = e / 241, idx = e - px * 241;
        int dy = idx >> 4, dx = idx & 15;
        int hy = y + dy - 7, hx = x0 + px + dx - 7;
        bool valid = (dx < 15) && (dy < 15) &&
                     (hy >= 0) && (hy < 32) && (hx >= 0) && (hx < 32);
        if (!valid) qk[e] = -1e8f;
    }
    __syncthreads();

    // ---- phase B: band QK^T ----
    for (int dy = wave; dy < 15; dy += 4) {
        const int ky = y + dy - 7;
        if (ky < 0 || ky > 31) continue;
#pragma unroll
        for (int kxt = 0; kxt < 2; ++kxt) {
            const int kxg = x0 - 8 + kxt * 16 + n16;
            const long kb = (((long)bz << 10) + ky * 32 + kxg) * 128 + quad * 8;
            floatx4 acc = {0.f, 0.f, 0.f, 0.f};
#pragma unroll
            for (int ch = 0; ch < 4; ++ch) {
                short8 b_hi = *(const short8*)(khi + kb + ch * 32);
                short8 b_lo = *(const short8*)(klo + kb + ch * 32);
                acc = __builtin_amdgcn_mfma_f32_16x16x32_bf16(a_hi[ch], b_hi, acc, 0, 0, 0);
                acc = __builtin_amdgcn_mfma_f32_16x16x32_bf16(a_hi[ch], b_lo, acc, 0, 0, 0);
                acc = __builtin_amdgcn_mfma_f32_16x16x32_bf16(a_lo[ch], b_hi, acc, 0, 0, 0);
            }
            if (kxg >= 0 && kxg < 32) {
#pragma unroll
                for (int r = 0; r < 4; ++r) {
                    int m = quad * 4 + r;
                    int dx = kxg - (x0 + m) + 7;
                    if (dx >= 0 && dx < 15) {
                        int s = m * 241 + dy * 16 + dx;
                        qk[s] = qk[s] + acc[r];
                    }
                }
            }
        }
    }
    __syncthreads();

    // ---- softmax ----
    {
        int px = tid >> 4, s = tid & 15;
        float mx = -3.0e38f;
        for (int w = s; w < 240; w += 16) mx = fmaxf(mx, qk[px * 241 + w]);
#pragma unroll
        for (int msk = 8; msk; msk >>= 1) mx = fmaxf(mx, __shfl_xor(mx, msk));
        float sum = 0.f;
        for (int w = s; w < 240; w += 16) {
            float p = __expf(qk[px * 241 + w] - mx);
            qk[px * 241 + w] = p;
            sum += p;
        }
#pragma unroll
        for (int msk = 8; msk; msk >>= 1) sum += __shfl_xor(sum, msk);
        if (s == 0) invl[px] = 1.0f / sum;
    }
    __syncthreads();

    // ---- normalized attention writeback ----
    for (int e = tid; e < 3600; e += 256) {
        int px = e & 15, w = e >> 4;
        int dy2 = w / 15, dx2 = w - dy2 * 15;
        relh[((long)w << 10) + y * 32 + x0 + px] =
            qk[px * 241 + dy2 * 16 + dx2] * invl[px];
    }
}

// ---------------------------------------------------------------------------
// pv (round-12 v5): full-dy blocks, frag epilogue.
// grid (y 32, chh 2, bz 8) = 512 blocks; thread = 2 ch x 4 px, 15 dy.
// ---------------------------------------------------------------------------
__global__ __launch_bounds__(256)
void pv_kernel(const float* __restrict__ vpad, const float* __restrict__ attn,
               const float* __restrict__ Vbias,
               short* __restrict__ AGhi, short* __restrict__ AGlo)
{
    __shared__ __align__(16) float pa[225 * 32];   // 28.8 KB, reused as tile
    const int tid = threadIdx.x;
    const int y   = blockIdx.x;
    const int chh = blockIdx.y;
    const int bz  = blockIdx.z;
    const int n = bz >> 1, g = bz & 1;

    const float* ab = attn + (long)bz * 230400 + y * 32;
    for (int e = tid; e < 1800; e += 256) {
        int w = e >> 3, x4 = (e & 7) * 4;
        *(float4*)&pa[w * 32 + x4] = *(const float4*)&ab[((long)w << 10) + x4];
    }
    __syncthreads();

    const int chg = tid >> 3;            // 0..31 -> 2 channels each
    const int xq  = tid & 7;
    const int c0  = chh * 64 + chg * 2;  // channel base within head
    const int x0  = xq * 4;
    const float* v0 = vpad + (long)bz * 196608 + (long)c0 * 1536;
    const float* v1 = v0 + 1536;
    const float* b0 = Vbias + (g * 128 + c0) * 225;
    const float* b1 = b0 + 225;

    float acc0[4] = {0.f, 0.f, 0.f, 0.f};
    float acc1[4] = {0.f, 0.f, 0.f, 0.f};

    for (int dy = 0; dy < 15; ++dy) {
        int hy = y + dy - 7;
        if (hy < 0 || hy > 31) continue;           // p == 0 for this dy
        const float4* r0 = (const float4*)(v0 + hy * 48 + x0);
        const float4* r1 = (const float4*)(v1 + hy * 48 + x0);
        float wa[20], wb[20];
#pragma unroll
        for (int t = 0; t < 5; ++t) {
            float4 a = r0[t], b = r1[t];
            wa[4*t+0] = a.x; wa[4*t+1] = a.y; wa[4*t+2] = a.z; wa[4*t+3] = a.w;
            wb[4*t+0] = b.x; wb[4*t+1] = b.y; wb[4*t+2] = b.z; wb[4*t+3] = b.w;
        }
        const float* par = &pa[dy * 15 * 32 + x0];
        const float* vb0 = b0 + dy * 15;
        const float* vb1 = b1 + dy * 15;
#pragma unroll
        for (int dx = 0; dx < 15; ++dx) {
            float4 p4 = *(const float4*)&par[dx * 32];
            float ba = vb0[dx], bb = vb1[dx];
            acc0[0] += p4.x * (wa[1 + dx] + ba);
            acc0[1] += p4.y * (wa[2 + dx] + ba);
            acc0[2] += p4.z * (wa[3 + dx] + ba);
            acc0[3] += p4.w * (wa[4 + dx] + ba);
            acc1[0] += p4.x * (wb[1 + dx] + bb);
            acc1[1] += p4.y * (wb[2 + dx] + bb);
            acc1[2] += p4.z * (wb[3 + dx] + bb);
            acc1[3] += p4.w * (wb[4 + dx] + bb);
        }
    }
    __syncthreads();                     // pa reads done -> reuse as tile

    float* tile = pa;                    // [32 m][65 c]
#pragma unroll
    for (int i = 0; i < 4; ++i) {
        tile[(x0 + i) * 65 + chg * 2 + 0] = acc0[i];
        tile[(x0 + i) * 65 + chg * 2 + 1] = acc1[i];
    }
    __syncthreads();

    // frag conversion: thread -> (mtp, kcp, lane)
    const int lane = tid & 63, sub = tid >> 6;
    const int kcp = sub & 1, mtp = sub >> 1;
    const int n16 = lane & 15, quad = lane >> 4;
    const int m_loc = mtp * 16 + n16;
    const int c_loc = kcp * 32 + quad * 8;
    short h[8], l[8];
#pragma unroll
    for (int j = 0; j < 8; ++j) {
        float f = tile[m_loc * 65 + c_loc + j];
        short hb = f2bf(f);
        h[j] = hb;
        l[j] = f2bf(f - bf2f(hb));
    }
    const int mt16 = y * 2 + mtp;
    const int kc = g * 4 + chh * 2 + kcp;
    long off = (long)n * 262144 + (((long)(mt16 * 8 + kc) * 64) + lane) * 8;
    *(short8*)(AGhi + off) = *(short8*)&h[0];
    *(short8*)(AGlo + off) = *(short8*)&l[0];
}

// ---------------------------------------------------------------------------
// mfma_fc v2: one m-tile per block. grid (mt16 64, db 4, nz 4) = 1024 blocks.
// ---------------------------------------------------------------------------
__global__ __launch_bounds__(256)
void mfma_fc(const short* __restrict__ Ahi, const short* __restrict__ Alo,
             const short* __restrict__ Whi, const short* __restrict__ Wlo,
             const float* __restrict__ bfc, float* __restrict__ out)
{
    __shared__ float tile[16 * 68];
    const int tid = threadIdx.x;
    const int wave = tid >> 6, lane = tid & 63;
    const int n16 = lane & 15, quad = lane >> 4;
    const int mt16 = blockIdx.x, db = blockIdx.y, nz = blockIdx.z;
    const int dt = db * 4 + wave;

    const short* Ah = Whi + (long)3 * 65536 + ((long)(dt * 8) * 64 + lane) * 8;
    const short* Al = Wlo + (long)3 * 65536 + ((long)(dt * 8) * 64 + lane) * 8;
    const short* Bh = Ahi + (long)nz * 262144;
    const short* Bl = Alo + (long)nz * 262144;

    float4 bv4 = *(const float4*)&bfc[dt * 16 + quad * 4];
    float bb[4] = {bv4.x, bv4.y, bv4.z, bv4.w};

    floatx4 acc = {0.f, 0.f, 0.f, 0.f};
#pragma unroll
    for (int kc = 0; kc < 8; ++kc) {
        short8 ahi = *(const short8*)(Ah + kc * 512);
        short8 alo = *(const short8*)(Al + kc * 512);
        long bo = ((long)(mt16 * 8 + kc) * 64 + lane) * 8;
        short8 bh = *(const short8*)(Bh + bo);
        short8 bl = *(const short8*)(Bl + bo);
        acc = __builtin_amdgcn_mfma_f32_16x16x32_bf16(ahi, bh, acc, 0, 0, 0);
        acc = __builtin_amdgcn_mfma_f32_16x16x32_bf16(ahi, bl, acc, 0, 0, 0);
        acc = __builtin_amdgcn_mfma_f32_16x16x32_bf16(alo, bh, acc, 0, 0, 0);
    }

    const int dl = wave * 16 + quad * 4;
#pragma unroll
    for (int r = 0; r < 4; ++r)
        tile[n16 * 68 + dl + r] = acc[r] + bb[r];
    __syncthreads();

    const int mm = tid >> 4, d4 = (tid & 15) * 4;
    float4 o4 = *(const float4*)&tile[mm * 68 + d4];
    *(float4*)&out[(long)(mt16 * 16 + mm) * 1024 + nz * 256 + db * 64 + d4] = o4;
}

// ---------------------------------------------------------------------------
// ws floats: vpad@2097152(1572864) attn@4718592(1843200)
//   qhi@6561792 qlo@7086080 khi@7610368 klo@8134656 (as shorts, 524288 fl ea)
//   Xhi@8658944(1572864) Xlo@10231808 Whi@11804672(131072) Wlo@11935744
//   AGhi@12066816(524288) AGlo@12591104 Wrh@13115392(30720) Wrl@13146112
// ---------------------------------------------------------------------------
extern "C" void kernel_launch(void* const* d_in, const int* in_sizes, int n_in,
                              void* d_out, int out_size, void* d_ws, size_t ws_size,
                              hipStream_t stream)
{
    const float* q    = (const float*)d_in[0];
    const float* k    = (const float*)d_in[1];
    const float* v    = (const float*)d_in[2];
    const float* Wq   = (const float*)d_in[3];
    const float* bq   = (const float*)d_in[4];
    const float* Wk   = (const float*)d_in[5];
    const float* bk   = (const float*)d_in[6];
    const float* Wv   = (const float*)d_in[7];
    const float* bv   = (const float*)d_in[8];
    const float* Wrel = (const float*)d_in[9];
    const float* brel = (const float*)d_in[10];
    const float* Vb   = (const float*)d_in[11];
    const float* Wfc  = (const float*)d_in[12];
    const float* bfc  = (const float*)d_in[13];
    float* out = (float*)d_out;

    float* ws   = (float*)d_ws;
    float* vpad = ws + 2097152;
    float* attn = ws + 4718592;
    short* qhi  = (short*)(ws + 6561792);
    short* qlo  = (short*)(ws + 7086080);
    short* khi  = (short*)(ws + 7610368);
    short* klo  = (short*)(ws + 8134656);
    short* Xhi  = (short*)(ws + 8658944);
    short* Xlo  = (short*)(ws + 10231808);
    short* Whi  = (short*)(ws + 11804672);
    short* Wlo  = (short*)(ws + 11935744);
    short* AGhi = (short*)(ws + 12066816);
    short* AGlo = (short*)(ws + 12591104);
    short* Wrh  = (short*)(ws + 13115392);
    short* Wrl  = (short*)(ws + 13146112);

    dim3 blk(256);

    // fragment conversion: inputs (z 0..11), weights (z 12..15), Wrel (16..17)
    conv_kernel<<<dim3(16, 8, 18), blk, 0, stream>>>(q, k, v, Wq, Wk, Wv, Wfc,
                                                     Wrel, Xhi, Xlo, Whi, Wlo,
                                                     Wrh, Wrl);

    // QKV projections via MFMA (vpad pads zeroed in-kernel): 3072 blocks
    mfma_proj<<<dim3(64, 4, 12), blk, 0, stream>>>(Xhi, Xlo, Whi, Wlo,
                                                   bq, bk, bv,
                                                   qhi, qlo, khi, klo, vpad);

    // rel + scores + softmax -> attn: 512 blocks
    scores_mfma<<<dim3(64, 8), blk, 0, stream>>>(qhi, qlo, khi, klo,
                                                 Wrh, Wrl, brel, attn);

    // PV + V_bias -> AG frags: 512 blocks
    pv_kernel<<<dim3(32, 2, 8), blk, 0, stream>>>(vpad, attn, Vb, AGhi, AGlo);

    // FC via MFMA, interleaved [m][n][c] store: 1024 blocks
    mfma_fc<<<dim3(64, 4, 4), blk, 0, stream>>>(AGhi, AGlo, Whi, Wlo, bfc, out);
}